// Round 5
// baseline (1100.968 us; speedup 1.0000x reference)
//
#include <hip/hip_runtime.h>
#include <hip/hip_bf16.h>

typedef __hip_bfloat16 bf16;
#define DEV __device__ __forceinline__

DEV float b2f(bf16 x) { return __bfloat162float(x); }
DEV bf16  f2b(float x) { return __float2bfloat16(x); }

typedef __attribute__((ext_vector_type(8))) short short8;   // 8 bf16 (4 VGPRs)
typedef __attribute__((ext_vector_type(4))) float f32x4;

static constexpr int B = 8, C = 128, S = 16;
static constexpr int L = S * S * S;                 // 4096
static constexpr size_t BL   = (size_t)B * L;       // 32768 tokens
static constexpr size_t VOLE = BL * C;              // 4,194,304 elements / volume

// ---- canonical f32 weight region (element offsets) ----
static constexpr size_t W_PW1  = 0;
static constexpr size_t W_PW1B = 163840;
static constexpr size_t W_LN1G = 165120;
static constexpr size_t W_LN1B = 166400;
static constexpr size_t W_DWW  = 167680;
static constexpr size_t W_DWB  = 202240;
static constexpr size_t W_LN2G = 203520;
static constexpr size_t W_LN2B = 204800;
static constexpr size_t W_PW2  = 206080;
static constexpr size_t W_PW2B = 369920;
static constexpr size_t W_LN3G = 371200;
static constexpr size_t W_LN3B = 372480;

// ---- workspace layout (bytes). ~142 MB. ----
static constexpr size_t OFF_FLAG = 0;
static constexpr size_t OFF_WTS  = 256;
static constexpr size_t OFF_WHI1 = 1572864;
static constexpr size_t OFF_WLO1 = OFF_WHI1 + 327680;
static constexpr size_t OFF_WHI2 = OFF_WLO1 + 327680;
static constexpr size_t OFF_WLO2 = OFF_WHI2 + 327680;
static constexpr size_t OFF_T    = 4u << 20;                // f32 [B,L,C] transposed vol (persist)
static constexpr size_t OFF_A    = OFF_T  + VOLE * 4;       // f32 chain temp
static constexpr size_t OFF_BB   = OFF_A  + VOLE * 4;       // f32 chain temp
static constexpr size_t OFF_X    = OFF_BB + VOLE * 4;       // f32 attention out
static constexpr size_t OFF_ATT  = OFF_X  + VOLE * 4;       // f32 [B,128,512]
static constexpr size_t OFF_QT   = OFF_ATT + (size_t)B * 128 * 512 * 4; // bf16 [B,C,L]
static constexpr size_t OFF_KT   = OFF_QT + VOLE * 2;       // bf16 [4][B,C,L]
static constexpr size_t OFF_VB   = OFF_KT + VOLE * 8;       // bf16 [4][B,L,C]

DEV float gelu(float x) { return 0.5f * x * (1.f + erff(x * 0.70710678118654752f)); }

__global__ void k_sniff(const unsigned* __restrict__ q, int* __restrict__ flag) {
  int t = threadIdx.x;
  unsigned u = q[t];
  int good = 0;
  #pragma unroll
  for (int h = 0; h < 2; ++h) {
    unsigned hb = (h ? (u & 0xffff0000u) : (u << 16));
    float v = __uint_as_float(hb);
    float a = fabsf(v);
    if (v == 0.f || (a > 1e-20f && a < 100.f)) good++;
  }
  #pragma unroll
  for (int off = 32; off; off >>= 1) good += __shfl_down(good, off);
  if (t == 0) *flag = (good >= 112) ? 1 : 0;
}

__global__ void k_cvt(const void* __restrict__ src, float* __restrict__ dst, int n,
                      const int* __restrict__ flagp) {
  int i = blockIdx.x * 256 + threadIdx.x;
  if (i >= n) return;
  if (*flagp) dst[i] = b2f(((const bf16*)src)[i]);
  else        dst[i] = ((const float*)src)[i];
}

__global__ void k_cvtw(const void* __restrict__ src, float* __restrict__ dst,
                       bf16* __restrict__ dhi, bf16* __restrict__ dlo, int n,
                       const int* __restrict__ flagp) {
  int i = blockIdx.x * 256 + threadIdx.x;
  if (i >= n) return;
  float v = (*flagp) ? b2f(((const bf16*)src)[i]) : ((const float*)src)[i];
  dst[i] = v;
  bf16 h = f2b(v);
  dhi[i] = h;
  dlo[i] = f2b(v - b2f(h));
}

// [B,C,L] -> [B,L,C] for ONE volume, LDS-tiled, dtype-branched loads, f32 out.
__global__ __launch_bounds__(256) void k_transpose(const void* __restrict__ sv,
                                                   float* __restrict__ d,
                                                   const int* __restrict__ flagp) {
  __shared__ float t[32][33];
  bool isb = (*flagp != 0);
  int b = blockIdx.z;
  int c0 = blockIdx.y * 32, l0 = blockIdx.x * 32;
  int tid = threadIdx.x;
  int lr = tid & 31, cr = tid >> 5;
  #pragma unroll
  for (int i = 0; i < 4; ++i) {
    size_t si = ((size_t)b * C + (c0 + cr + i * 8)) * L + l0 + lr;
    t[cr + i * 8][lr] = isb ? b2f(((const bf16*)sv)[si]) : ((const float*)sv)[si];
  }
  __syncthreads();
  int cw = tid & 31, lw = tid >> 5;
  #pragma unroll
  for (int i = 0; i < 4; ++i) {
    int l = l0 + lw + i * 8;
    d[((size_t)b * L + l) * C + c0 + cw] = t[cw][lw + i * 8];
  }
}

// ---- pointwise conv via split-precision MFMA + fused bias+LN(+GELU) + fused output cast. ----
// Tile 64 tokens x 128 outputs, 256 thr (4 waves), grid 512. LDS 34.8 KB -> 4 blocks/CU cap.
// OUTMODE: 0 = f32 [l][c], 1 = bf16 [l][c], 2 = bf16 [c][l] (transposed, for q/K).
template <bool DOGELU, bool XEXACT, int OUTMODE>
__global__ __launch_bounds__(256) void k_pw_mfma(
    const float* __restrict__ in, void* __restrict__ outv,
    const bf16* __restrict__ Whi, const bf16* __restrict__ Wlo,
    const float* __restrict__ bias,
    const float* __restrict__ gam, const float* __restrict__ bet, int blk,
    const int* __restrict__ flagp) {
  __shared__ __align__(16) char smem[64 * 136 * 2 * 2];   // 34,816 B
  bf16* xh = (bf16*)smem;                                 // [64][136]
  bf16* xl = (bf16*)(smem + 64 * 136 * 2);
  float* ys = (float*)smem;                               // [64][133] = 34,048 B (alias)
  int t = threadIdx.x;
  bool ex = XEXACT && (*flagp != 0);
  size_t tok0 = (size_t)blockIdx.x * 64;
  const bf16* Wh = Whi + ((size_t)blk << 14);
  const bf16* Wl = Wlo + ((size_t)blk << 14);
  // stage x hi/lo: 64 tokens x 128 ch
  #pragma unroll
  for (int p = 0; p < 8; ++p) {
    int idx = p * 256 + t;
    int m = idx >> 5, c4 = (idx & 31) * 4;
    float4 v = *(const float4*)(in + (tok0 + m) * 128 + c4);
    bf16 hi[4] = {f2b(v.x), f2b(v.y), f2b(v.z), f2b(v.w)};
    *(ushort4*)(xh + m * 136 + c4) = *(ushort4*)hi;
    if (!ex) {
      bf16 lo[4] = {f2b(v.x - b2f(hi[0])), f2b(v.y - b2f(hi[1])),
                    f2b(v.z - b2f(hi[2])), f2b(v.w - b2f(hi[3]))};
      *(ushort4*)(xl + m * 136 + c4) = *(ushort4*)lo;
    }
  }
  __syncthreads();
  int w = t >> 6, lane = t & 63;
  int wm = (w & 1) * 32, wo = (w >> 1) * 64;   // wave: 32 tokens x 64 outputs
  int cl = lane & 15, q = lane >> 4;
  f32x4 acc[2][4] = {};
  #pragma unroll
  for (int ks = 0; ks < 4; ++ks) {
    int k = ks * 32 + q * 8;
    short8 ah[2], al[2], bh[4], blo[4];
    #pragma unroll
    for (int i = 0; i < 2; ++i) {
      ah[i] = *(const short8*)(xh + (wm + i * 16 + cl) * 136 + k);
      if (!ex) al[i] = *(const short8*)(xl + (wm + i * 16 + cl) * 136 + k);
    }
    #pragma unroll
    for (int j = 0; j < 4; ++j) {
      size_t wi = (size_t)(wo + j * 16 + cl) * 128 + k;
      bh[j]  = *(const short8*)(Wh + wi);
      blo[j] = *(const short8*)(Wl + wi);
    }
    #pragma unroll
    for (int i = 0; i < 2; ++i)
      #pragma unroll
      for (int j = 0; j < 4; ++j) {
        acc[i][j] = __builtin_amdgcn_mfma_f32_16x16x32_bf16(ah[i], bh[j],  acc[i][j], 0, 0, 0);
        acc[i][j] = __builtin_amdgcn_mfma_f32_16x16x32_bf16(ah[i], blo[j], acc[i][j], 0, 0, 0);
        if (!ex)
          acc[i][j] = __builtin_amdgcn_mfma_f32_16x16x32_bf16(al[i], bh[j], acc[i][j], 0, 0, 0);
      }
  }
  float blv[4];
  #pragma unroll
  for (int j = 0; j < 4; ++j) blv[j] = bias[blk * 128 + wo + j * 16 + cl];
  __syncthreads();
  // park D+bias into ys[64][133]
  #pragma unroll
  for (int i = 0; i < 2; ++i)
    #pragma unroll
    for (int j = 0; j < 4; ++j)
      #pragma unroll
      for (int r = 0; r < 4; ++r)
        ys[(wm + i * 16 + q * 4 + r) * 133 + wo + j * 16 + cl] = acc[i][j][r] + blv[j];
  __syncthreads();
  // LN: 4 threads per token, each 32 channels
  int m = t >> 2, qtr = t & 3;
  float* yr = ys + (size_t)m * 133 + qtr * 32;
  float s = 0.f, q2 = 0.f;
  #pragma unroll
  for (int jj = 0; jj < 8; ++jj) {
    float4 v = *(const float4*)(yr + jj * 4);
    s  += v.x + v.y + v.z + v.w;
    q2 += v.x * v.x + v.y * v.y + v.z * v.z + v.w * v.w;
  }
  s += __shfl_xor(s, 1);  q2 += __shfl_xor(q2, 1);
  s += __shfl_xor(s, 2);  q2 += __shfl_xor(q2, 2);
  float mean = s * (1.f / 128.f);
  float var = fmaxf(q2 * (1.f / 128.f) - mean * mean, 0.f);
  float rstd = rsqrtf(var + 1e-6f);
  #pragma unroll
  for (int jj = 0; jj < 8; ++jj) {
    int c = qtr * 32 + jj * 4;
    float4 v = *(const float4*)(yr + jj * 4);
    float4 g = *(const float4*)(gam + blk * 128 + c);
    float4 e = *(const float4*)(bet + blk * 128 + c);
    float4 r;
    r.x = (v.x - mean) * rstd * g.x + e.x;
    r.y = (v.y - mean) * rstd * g.y + e.y;
    r.z = (v.z - mean) * rstd * g.z + e.z;
    r.w = (v.w - mean) * rstd * g.w + e.w;
    if (DOGELU) { r.x = gelu(r.x); r.y = gelu(r.y); r.z = gelu(r.z); r.w = gelu(r.w); }
    if (OUTMODE == 0) {
      *(float4*)((float*)outv + (tok0 + m) * 128 + c) = r;
    } else if (OUTMODE == 1) {
      bf16 o[4] = {f2b(r.x), f2b(r.y), f2b(r.z), f2b(r.w)};
      *(ushort4*)((bf16*)outv + (tok0 + m) * 128 + c) = *(ushort4*)o;
    } else {
      *(float4*)(yr + jj * 4) = r;   // write back for transposed pass
    }
  }
  if (OUTMODE == 2) {
    __syncthreads();
    // transposed store: out[b*128+c][l0 + l], 2 threads per c (32 l each)
    int b = (int)(tok0 >> 12), l0 = (int)(tok0 & 4095);
    int c = t >> 1, lh = (t & 1) * 32;
    bf16 tmp[32];
    #pragma unroll
    for (int i = 0; i < 32; ++i) tmp[i] = f2b(ys[(size_t)(lh + i) * 133 + c]);
    bf16* dst = (bf16*)outv + ((size_t)b * 128 + c) * 4096 + l0 + lh;
    #pragma unroll
    for (int i = 0; i < 4; ++i) *(uint4*)(dst + i * 8) = *(uint4*)(tmp + i * 8);
  }
}

// ---- depthwise 3x3x3 + bias + LN + GELU. 512 thr: (cq 32) x (zg 16), 1 z each. ----
__global__ __launch_bounds__(512) void k_dw_ln(
    const float* __restrict__ in, float* __restrict__ out,
    const float* __restrict__ W, const float* __restrict__ bias,
    const float* __restrict__ gam, const float* __restrict__ bet, int blk) {
  __shared__ __align__(16) float ls[9][16][128];   // 73,728 B
  __shared__ __align__(16) float dww[27][128];     // 13,824 B
  int t = threadIdx.x;
  int xg = blockIdx.x & 15, yg = (blockIdx.x >> 4) & 15, b = blockIdx.x >> 8;
  const float* base = in + (((size_t)b) << 12) * 128;
  const float* Wb = W + (size_t)blk * 3456;
  for (int idx = t; idx < 3456; idx += 512) {
    int tap = idx >> 7, c = idx & 127;
    dww[tap][c] = Wb[c * 27 + tap];
  }
  {
    int c4 = (t & 31) * 4, zz = t >> 5;   // zz 0..15
    for (int col = 0; col < 9; ++col) {
      int yy = yg + col / 3 - 1, xx = xg + col % 3 - 1;
      bool ok = ((unsigned)yy < 16u) && ((unsigned)xx < 16u);
      float4 v = {0.f, 0.f, 0.f, 0.f};
      if (ok) v = *(const float4*)(base + ((size_t)((zz << 8) | (yy << 4) | xx)) * 128 + c4);
      *(float4*)&ls[col][zz][c4] = v;
    }
  }
  __syncthreads();
  int q = t & 31, zg = t >> 5;   // zg 0..15 = z
  int c0 = q * 4;
  float4 bias4 = *(const float4*)(bias + blk * 128 + c0);
  float acc[4] = {bias4.x, bias4.y, bias4.z, bias4.w};
  #pragma unroll
  for (int ky = 0; ky < 3; ++ky) {
    #pragma unroll
    for (int kx = 0; kx < 3; ++kx) {
      int col = ky * 3 + kx;
      #pragma unroll
      for (int kz = 0; kz < 3; ++kz) {
        int z = zg + kz - 1;
        float4 v = {0.f, 0.f, 0.f, 0.f};
        if ((unsigned)z < 16u) v = *(const float4*)&ls[col][z][c0];
        float4 w4 = *(const float4*)&dww[kz * 9 + col][c0];
        acc[0] += w4.x * v.x;
        acc[1] += w4.y * v.y;
        acc[2] += w4.z * v.z;
        acc[3] += w4.w * v.w;
      }
    }
  }
  float4 g4 = *(const float4*)(gam + blk * 128 + c0);
  float4 e4 = *(const float4*)(bet + blk * 128 + c0);
  float s  = acc[0] + acc[1] + acc[2] + acc[3];
  float qq = acc[0] * acc[0] + acc[1] * acc[1] + acc[2] * acc[2] + acc[3] * acc[3];
  #pragma unroll
  for (int off = 16; off; off >>= 1) {
    s  += __shfl_down(s, off, 32);
    qq += __shfl_down(qq, off, 32);
  }
  s = __shfl(s, 0, 32); qq = __shfl(qq, 0, 32);
  float mean = s * (1.f / 128.f);
  float var = fmaxf(qq * (1.f / 128.f) - mean * mean, 0.f);
  float rstd = rsqrtf(var + 1e-6f);
  float4 r;
  r.x = gelu((acc[0] - mean) * rstd * g4.x + e4.x);
  r.y = gelu((acc[1] - mean) * rstd * g4.y + e4.y);
  r.z = gelu((acc[2] - mean) * rstd * g4.z + e4.z);
  r.w = gelu((acc[3] - mean) * rstd * g4.w + e4.w);
  *(float4*)(out + (((size_t)b << 12) | (zg << 8) | (yg << 4) | xg) * 128 + c0) = r;
}

// ---- qk via MFMA ----
__global__ __launch_bounds__(256) void k_qk_mfma(
    const bf16* __restrict__ qT, const bf16* __restrict__ kT,
    float* __restrict__ attn) {
  __shared__ __align__(16) bf16 qs[128 * 72];
  __shared__ __align__(16) bf16 ks[128 * 72];
  int ls = blockIdx.x, ki = blockIdx.y, b = blockIdx.z;
  const bf16* qb = qT + ((size_t)b * 128) * 4096;
  const bf16* kb = kT + (((size_t)ki * 8 + b) * 128) * 4096;
  int t = threadIdx.x;
  int w = t >> 6, lane = t & 63;
  int wm = (w >> 1) * 64, wo = (w & 1) * 64;
  int cl = lane & 15, q = lane >> 4;
  f32x4 acc[4][4] = {};
  for (int lc = 0; lc < 8; ++lc) {
    int l0 = ls * 512 + lc * 64;
    #pragma unroll
    for (int p = 0; p < 4; ++p) {
      int idx = p * 256 + t;
      int r = idx >> 3, l8 = (idx & 7) * 8;
      *(uint4*)(qs + r * 72 + l8) = *(const uint4*)(qb + (size_t)r * 4096 + l0 + l8);
      *(uint4*)(ks + r * 72 + l8) = *(const uint4*)(kb + (size_t)r * 4096 + l0 + l8);
    }
    __syncthreads();
    #pragma unroll
    for (int kstep = 0; kstep < 2; ++kstep) {
      int kk = kstep * 32 + q * 8;
      short8 a[4], bb[4];
      #pragma unroll
      for (int i = 0; i < 4; ++i) a[i]  = *(const short8*)(qs + (wm + i * 16 + cl) * 72 + kk);
      #pragma unroll
      for (int j = 0; j < 4; ++j) bb[j] = *(const short8*)(ks + (wo + j * 16 + cl) * 72 + kk);
      #pragma unroll
      for (int i = 0; i < 4; ++i)
        #pragma unroll
        for (int j = 0; j < 4; ++j)
          acc[i][j] = __builtin_amdgcn_mfma_f32_16x16x32_bf16(a[i], bb[j], acc[i][j], 0, 0, 0);
    }
    __syncthreads();
  }
  #pragma unroll
  for (int i = 0; i < 4; ++i)
    #pragma unroll
    for (int j = 0; j < 4; ++j)
      #pragma unroll
      for (int r = 0; r < 4; ++r) {
        int c = wm + i * 16 + q * 4 + r;
        int k = ki * 128 + wo + j * 16 + cl;
        atomicAdd(&attn[((size_t)b * 128 + c) * 512 + k], acc[i][j][r]);
      }
}

// masked softmax over k=512 per (b,c) row; scale = 1/64.
__global__ __launch_bounds__(128) void k_sm(float* __restrict__ attn, const int* __restrict__ mask) {
  __shared__ float rm[2], rs[2];
  int b = blockIdx.x >> 7;
  float* row = attn + (size_t)blockIdx.x * 512;
  int t = threadIdx.x;
  float v[4];
  #pragma unroll
  for (int j = 0; j < 4; ++j) {
    int k = t + j * 128;
    v[j] = (mask[b * 4 + j] > 0) ? row[k] * 0.015625f : -1e30f;
  }
  float m = fmaxf(fmaxf(v[0], v[1]), fmaxf(v[2], v[3]));
  #pragma unroll
  for (int off = 32; off; off >>= 1) m = fmaxf(m, __shfl_down(m, off));
  if ((t & 63) == 0) rm[t >> 6] = m;
  __syncthreads();
  m = fmaxf(rm[0], rm[1]);
  float e[4], s = 0.f;
  #pragma unroll
  for (int j = 0; j < 4; ++j) { e[j] = expf(v[j] - m); s += e[j]; }
  #pragma unroll
  for (int off = 32; off; off >>= 1) s += __shfl_down(s, off);
  if ((t & 63) == 0) rs[t >> 6] = s;
  __syncthreads();
  float inv = 1.f / (rs[0] + rs[1]);
  #pragma unroll
  for (int j = 0; j < 4; ++j) row[t + j * 128] = e[j] * inv;
}

// ---- av via MFMA ----
__global__ __launch_bounds__(256) void k_av_mfma(
    const float* __restrict__ attn, const bf16* __restrict__ vball,
    float* __restrict__ xout) {
  __shared__ __align__(16) bf16 vs[128 * 72];
  __shared__ __align__(16) bf16 ps[128 * 72];
  int lt = blockIdx.x, b = blockIdx.y;
  int t = threadIdx.x;
  int w = t >> 6, lane = t & 63;
  int wm = (w >> 1) * 64, wo = (w & 1) * 64;
  int cl = lane & 15, q = lane >> 4;
  f32x4 acc[4][4] = {};
  for (int ki = 0; ki < 4; ++ki) {
    const bf16* vbp = vball + (((size_t)ki * 8 + b) * L) * 128;
    for (int kc = 0; kc < 2; ++kc) {
      #pragma unroll
      for (int p = 0; p < 4; ++p) {
        int idx = p * 256 + t;
        int r = idx >> 3, k8 = (idx & 7) * 8;
        *(uint4*)(vs + r * 72 + k8) =
            *(const uint4*)(vbp + (size_t)(lt * 128 + r) * 128 + kc * 64 + k8);
      }
      #pragma unroll
      for (int p = 0; p < 8; ++p) {
        int idx = p * 256 + t;
        int c = idx >> 4, k4 = (idx & 15) * 4;
        float4 v = *(const float4*)&attn[((size_t)b * 128 + c) * 512 + ki * 128 + kc * 64 + k4];
        bf16 o[4] = {f2b(v.x), f2b(v.y), f2b(v.z), f2b(v.w)};
        *(ushort4*)(ps + c * 72 + k4) = *(ushort4*)o;
      }
      __syncthreads();
      #pragma unroll
      for (int kstep = 0; kstep < 2; ++kstep) {
        int kk = kstep * 32 + q * 8;
        short8 a[4], bb[4];
        #pragma unroll
        for (int i = 0; i < 4; ++i) a[i]  = *(const short8*)(vs + (wm + i * 16 + cl) * 72 + kk);
        #pragma unroll
        for (int j = 0; j < 4; ++j) bb[j] = *(const short8*)(ps + (wo + j * 16 + cl) * 72 + kk);
        #pragma unroll
        for (int i = 0; i < 4; ++i)
          #pragma unroll
          for (int j = 0; j < 4; ++j)
            acc[i][j] = __builtin_amdgcn_mfma_f32_16x16x32_bf16(a[i], bb[j], acc[i][j], 0, 0, 0);
      }
      __syncthreads();
    }
  }
  #pragma unroll
  for (int i = 0; i < 4; ++i)
    #pragma unroll
    for (int j = 0; j < 4; ++j)
      #pragma unroll
      for (int r = 0; r < 4; ++r) {
        int l = lt * 128 + wm + i * 16 + q * 4 + r;
        int c = wo + j * 16 + cl;
        xout[((size_t)b * L + l) * 128 + c] = acc[i][j][r];
      }
}

// out[b,c,l] = query[b,c,l] + x9[b,l,c]
__global__ __launch_bounds__(256) void k_final(
    const void* __restrict__ qv, const float* __restrict__ xin, void* __restrict__ outv,
    const int* __restrict__ flagp) {
  __shared__ float tl[32][33];
  bool isb = (*flagp != 0);
  int l0 = blockIdx.x * 32, c0 = blockIdx.y * 32, b = blockIdx.z;
  int t = threadIdx.x;
  int cc = t & 31, lr = t >> 5;
  #pragma unroll
  for (int p = 0; p < 4; ++p) {
    int l = l0 + lr + p * 8;
    tl[lr + p * 8][cc] = xin[((((size_t)b) << 12) + l) * 128 + c0 + cc];
  }
  __syncthreads();
  int lw = t & 31, cr = t >> 5;
  #pragma unroll
  for (int p = 0; p < 4; ++p) {
    int c = c0 + cr + p * 8;
    size_t idx = (((size_t)b * 128 + c) << 12) + l0 + lw;
    float qf = isb ? b2f(((const bf16*)qv)[idx]) : ((const float*)qv)[idx];
    float r = qf + tl[lw][cr + p * 8];
    if (isb) ((bf16*)outv)[idx] = f2b(r);
    else     ((float*)outv)[idx] = r;
  }
}

extern "C" void kernel_launch(void* const* d_in, const int* in_sizes, int n_in,
                              void* d_out, int out_size, void* d_ws, size_t ws_size,
                              hipStream_t stream) {
  const void* vols[5] = {d_in[0], d_in[1], d_in[2], d_in[3], d_in[4]};
  const int* mask = (const int*)d_in[5];

  char* ws = (char*)d_ws;
  int*   flag  = (int*)(ws + OFF_FLAG);
  float* wts   = (float*)(ws + OFF_WTS);
  bf16*  whi1  = (bf16*)(ws + OFF_WHI1);
  bf16*  wlo1  = (bf16*)(ws + OFF_WLO1);
  bf16*  whi2  = (bf16*)(ws + OFF_WHI2);
  bf16*  wlo2  = (bf16*)(ws + OFF_WLO2);
  float* bufT  = (float*)(ws + OFF_T);
  float* bufA  = (float*)(ws + OFF_A);
  float* bufB  = (float*)(ws + OFF_BB);
  float* xattn = (float*)(ws + OFF_X);
  float* attn  = (float*)(ws + OFF_ATT);
  bf16*  qT    = (bf16*)(ws + OFF_QT);
  bf16*  kT    = (bf16*)(ws + OFF_KT);
  bf16*  vb    = (bf16*)(ws + OFF_VB);

  k_sniff<<<1, 64, 0, stream>>>((const unsigned*)d_in[0], flag);

  const size_t woff[12] = {W_PW1, W_PW1B, W_LN1G, W_LN1B, W_DWW, W_DWB,
                           W_LN2G, W_LN2B, W_PW2, W_PW2B, W_LN3G, W_LN3B};
  for (int i = 0; i < 12; ++i) {
    int n = in_sizes[6 + i];
    if (i == 0)
      k_cvtw<<<(n + 255) / 256, 256, 0, stream>>>(d_in[6 + i], wts + woff[i], whi1, wlo1, n, flag);
    else if (i == 8)
      k_cvtw<<<(n + 255) / 256, 256, 0, stream>>>(d_in[6 + i], wts + woff[i], whi2, wlo2, n, flag);
    else
      k_cvt<<<(n + 255) / 256, 256, 0, stream>>>(d_in[6 + i], wts + woff[i], n, flag);
  }
  const float *pw1_b = wts + W_PW1B, *ln1_g = wts + W_LN1G, *ln1_b = wts + W_LN1B;
  const float *dw_w = wts + W_DWW, *dw_b = wts + W_DWB, *ln2_g = wts + W_LN2G, *ln2_b = wts + W_LN2B;
  const float *pw2_b = wts + W_PW2B, *ln3_g = wts + W_LN3G, *ln3_b = wts + W_LN3B;

  dim3 tg(L / 32, 4, 8);
  hipMemsetAsync(attn, 0, (size_t)B * 128 * 512 * 4, stream);

  // chain: (bufT f32 in) -> pw1 -> bufA -> dw -> bufB -> pw2 -> dst (mode-dependent)
  auto chain = [&]<int OM>(std::integral_constant<int, OM>, const float* src, int blk, void* dst) {
    k_pw_mfma<true, true, 0><<<512, 256, 0, stream>>>(src, bufA, whi1, wlo1, pw1_b, ln1_g, ln1_b, blk, flag);
    k_dw_ln<<<2048, 512, 0, stream>>>(bufA, bufB, dw_w, dw_b, ln2_g, ln2_b, blk);
    k_pw_mfma<false, false, OM><<<512, 256, 0, stream>>>(bufB, dst, whi2, wlo2, pw2_b, ln3_g, ln3_b, blk, flag);
  };

  // q stream
  k_transpose<<<tg, 256, 0, stream>>>(vols[0], bufT, flag);
  chain(std::integral_constant<int, 2>{}, bufT, 0, qT);

  // K + V streams share one transpose per modality
  for (int m = 1; m <= 4; ++m) {
    k_transpose<<<tg, 256, 0, stream>>>(vols[m], bufT, flag);
    chain(std::integral_constant<int, 2>{}, bufT, m,     kT + (size_t)(m - 1) * VOLE);
    chain(std::integral_constant<int, 1>{}, bufT, 4 + m, vb + (size_t)(m - 1) * VOLE);
  }

  k_qk_mfma<<<dim3(8, 4, 8), 256, 0, stream>>>(qT, kT, attn);
  k_sm<<<(int)(B * 128), 128, 0, stream>>>(attn, mask);
  k_av_mfma<<<dim3(32, 8), 256, 0, stream>>>(attn, vb, xattn);

  // block 9 then residual
  k_pw_mfma<true, false, 0><<<512, 256, 0, stream>>>(xattn, bufA, whi1, wlo1, pw1_b, ln1_g, ln1_b, 9, flag);
  k_dw_ln<<<2048, 512, 0, stream>>>(bufA, bufB, dw_w, dw_b, ln2_g, ln2_b, 9);
  k_pw_mfma<false, false, 0><<<512, 256, 0, stream>>>(bufB, bufA, whi2, wlo2, pw2_b, ln3_g, ln3_b, 9, flag);
  k_final<<<dim3(L / 32, 4, 8), 256, 0, stream>>>(vols[0], bufA, d_out, flag);
}

// Round 8
// 1091.887 us; speedup vs baseline: 1.0083x; 1.0083x over previous
//
#include <hip/hip_runtime.h>
#include <hip/hip_bf16.h>

typedef __hip_bfloat16 bf16;
#define DEV __device__ __forceinline__

DEV float b2f(bf16 x) { return __bfloat162float(x); }
DEV bf16  f2b(float x) { return __float2bfloat16(x); }

typedef __attribute__((ext_vector_type(8))) short short8;   // 8 bf16 (4 VGPRs)
typedef __attribute__((ext_vector_type(4))) float f32x4;

static constexpr int B = 8, C = 128, S = 16;
static constexpr int L = S * S * S;                 // 4096
static constexpr size_t BL   = (size_t)B * L;       // 32768 tokens
static constexpr size_t VOLE = BL * C;              // 4,194,304 elements / volume

// ---- canonical f32 weight region (element offsets) ----
static constexpr size_t W_PW1  = 0;
static constexpr size_t W_PW1B = 163840;
static constexpr size_t W_LN1G = 165120;
static constexpr size_t W_LN1B = 166400;
static constexpr size_t W_DWW  = 167680;
static constexpr size_t W_DWB  = 202240;
static constexpr size_t W_LN2G = 203520;
static constexpr size_t W_LN2B = 204800;
static constexpr size_t W_PW2  = 206080;
static constexpr size_t W_PW2B = 369920;
static constexpr size_t W_LN3G = 371200;
static constexpr size_t W_LN3B = 372480;

// ---- workspace layout (bytes). ~142 MB (same as verified baseline). ----
static constexpr size_t OFF_FLAG = 0;
static constexpr size_t OFF_WTS  = 256;
static constexpr size_t OFF_WHI1 = 1572864;
static constexpr size_t OFF_WLO1 = OFF_WHI1 + 327680;
static constexpr size_t OFF_WHI2 = OFF_WLO1 + 327680;
static constexpr size_t OFF_WLO2 = OFF_WHI2 + 327680;
static constexpr size_t OFF_T    = 4u << 20;                // f32 [B,L,C] transposed vol (persist)
static constexpr size_t OFF_A    = OFF_T  + VOLE * 4;       // f32 chain temp
static constexpr size_t OFF_BB   = OFF_A  + VOLE * 4;       // f32 chain temp
static constexpr size_t OFF_X    = OFF_BB + VOLE * 4;       // f32: qk partials [8][B,128,512] then attn out [B,L,C]
static constexpr size_t OFF_ATT  = OFF_X  + VOLE * 4;       // f32 [B,128,512] softmax probs
static constexpr size_t OFF_QT   = OFF_ATT + (size_t)B * 128 * 512 * 4; // bf16 [B,C,L]
static constexpr size_t OFF_KT   = OFF_QT + VOLE * 2;       // bf16 [4][B,C,L]
static constexpr size_t OFF_VB   = OFF_KT + VOLE * 8;       // bf16 [4][B,L,C]

DEV float gelu(float x) { return 0.5f * x * (1.f + erff(x * 0.70710678118654752f)); }

__global__ void k_sniff(const unsigned* __restrict__ q, int* __restrict__ flag) {
  int t = threadIdx.x;
  unsigned u = q[t];
  int good = 0;
  #pragma unroll
  for (int h = 0; h < 2; ++h) {
    unsigned hb = (h ? (u & 0xffff0000u) : (u << 16));
    float v = __uint_as_float(hb);
    float a = fabsf(v);
    if (v == 0.f || (a > 1e-20f && a < 100.f)) good++;
  }
  #pragma unroll
  for (int off = 32; off; off >>= 1) good += __shfl_down(good, off);
  if (t == 0) *flag = (good >= 112) ? 1 : 0;
}

__global__ void k_cvt(const void* __restrict__ src, float* __restrict__ dst, int n,
                      const int* __restrict__ flagp) {
  int i = blockIdx.x * 256 + threadIdx.x;
  if (i >= n) return;
  if (*flagp) dst[i] = b2f(((const bf16*)src)[i]);
  else        dst[i] = ((const float*)src)[i];
}

__global__ void k_cvtw(const void* __restrict__ src, float* __restrict__ dst,
                       bf16* __restrict__ dhi, bf16* __restrict__ dlo, int n,
                       const int* __restrict__ flagp) {
  int i = blockIdx.x * 256 + threadIdx.x;
  if (i >= n) return;
  float v = (*flagp) ? b2f(((const bf16*)src)[i]) : ((const float*)src)[i];
  dst[i] = v;
  bf16 h = f2b(v);
  dhi[i] = h;
  dlo[i] = f2b(v - b2f(h));
}

// [B,C,L] -> [B,L,C] for ONE volume, LDS-tiled, dtype-branched loads, f32 out.
__global__ __launch_bounds__(256) void k_transpose(const void* __restrict__ sv,
                                                   float* __restrict__ d,
                                                   const int* __restrict__ flagp) {
  __shared__ float t[32][33];
  bool isb = (*flagp != 0);
  int b = blockIdx.z;
  int c0 = blockIdx.y * 32, l0 = blockIdx.x * 32;
  int tid = threadIdx.x;
  int lr = tid & 31, cr = tid >> 5;
  #pragma unroll
  for (int i = 0; i < 4; ++i) {
    size_t si = ((size_t)b * C + (c0 + cr + i * 8)) * L + l0 + lr;
    t[cr + i * 8][lr] = isb ? b2f(((const bf16*)sv)[si]) : ((const float*)sv)[si];
  }
  __syncthreads();
  int cw = tid & 31, lw = tid >> 5;
  #pragma unroll
  for (int i = 0; i < 4; ++i) {
    int l = l0 + lw + i * 8;
    d[((size_t)b * L + l) * C + c0 + cw] = t[cw][lw + i * 8];
  }
}

// ---- pointwise conv via split-precision MFMA + fused bias+LN(+GELU) + fused output cast. ----
// Tile 64 tokens x 128 outputs, 256 thr (4 waves), grid 512. LDS 34.8 KB -> 4 blocks/CU cap.
// OUTMODE: 0 = f32 [l][c], 1 = bf16 [l][c], 2 = bf16 [c][l] (transposed, for q/K).
template <bool DOGELU, bool XEXACT, int OUTMODE>
__global__ __launch_bounds__(256) void k_pw_mfma(
    const float* __restrict__ in, void* __restrict__ outv,
    const bf16* __restrict__ Whi, const bf16* __restrict__ Wlo,
    const float* __restrict__ bias,
    const float* __restrict__ gam, const float* __restrict__ bet, int blk,
    const int* __restrict__ flagp) {
  __shared__ __align__(16) char smem[64 * 136 * 2 * 2];   // 34,816 B
  bf16* xh = (bf16*)smem;                                 // [64][136]
  bf16* xl = (bf16*)(smem + 64 * 136 * 2);
  float* ys = (float*)smem;                               // [64][133] = 34,048 B (alias)
  int t = threadIdx.x;
  bool ex = XEXACT && (*flagp != 0);
  size_t tok0 = (size_t)blockIdx.x * 64;
  const bf16* Wh = Whi + ((size_t)blk << 14);
  const bf16* Wl = Wlo + ((size_t)blk << 14);
  // stage x hi/lo: 64 tokens x 128 ch
  #pragma unroll
  for (int p = 0; p < 8; ++p) {
    int idx = p * 256 + t;
    int m = idx >> 5, c4 = (idx & 31) * 4;
    float4 v = *(const float4*)(in + (tok0 + m) * 128 + c4);
    bf16 hi[4] = {f2b(v.x), f2b(v.y), f2b(v.z), f2b(v.w)};
    *(ushort4*)(xh + m * 136 + c4) = *(ushort4*)hi;
    if (!ex) {
      bf16 lo[4] = {f2b(v.x - b2f(hi[0])), f2b(v.y - b2f(hi[1])),
                    f2b(v.z - b2f(hi[2])), f2b(v.w - b2f(hi[3]))};
      *(ushort4*)(xl + m * 136 + c4) = *(ushort4*)lo;
    }
  }
  __syncthreads();
  int w = t >> 6, lane = t & 63;
  int wm = (w & 1) * 32, wo = (w >> 1) * 64;   // wave: 32 tokens x 64 outputs
  int cl = lane & 15, q = lane >> 4;
  f32x4 acc[2][4] = {};
  #pragma unroll
  for (int ks = 0; ks < 4; ++ks) {
    int k = ks * 32 + q * 8;
    short8 ah[2], al[2], bh[4], blo[4];
    #pragma unroll
    for (int i = 0; i < 2; ++i) {
      ah[i] = *(const short8*)(xh + (wm + i * 16 + cl) * 136 + k);
      if (!ex) al[i] = *(const short8*)(xl + (wm + i * 16 + cl) * 136 + k);
    }
    #pragma unroll
    for (int j = 0; j < 4; ++j) {
      size_t wi = (size_t)(wo + j * 16 + cl) * 128 + k;
      bh[j]  = *(const short8*)(Wh + wi);
      blo[j] = *(const short8*)(Wl + wi);
    }
    #pragma unroll
    for (int i = 0; i < 2; ++i)
      #pragma unroll
      for (int j = 0; j < 4; ++j) {
        acc[i][j] = __builtin_amdgcn_mfma_f32_16x16x32_bf16(ah[i], bh[j],  acc[i][j], 0, 0, 0);
        acc[i][j] = __builtin_amdgcn_mfma_f32_16x16x32_bf16(ah[i], blo[j], acc[i][j], 0, 0, 0);
        if (!ex)
          acc[i][j] = __builtin_amdgcn_mfma_f32_16x16x32_bf16(al[i], bh[j], acc[i][j], 0, 0, 0);
      }
  }
  float blv[4];
  #pragma unroll
  for (int j = 0; j < 4; ++j) blv[j] = bias[blk * 128 + wo + j * 16 + cl];
  __syncthreads();
  // park D+bias into ys[64][133]
  #pragma unroll
  for (int i = 0; i < 2; ++i)
    #pragma unroll
    for (int j = 0; j < 4; ++j)
      #pragma unroll
      for (int r = 0; r < 4; ++r)
        ys[(wm + i * 16 + q * 4 + r) * 133 + wo + j * 16 + cl] = acc[i][j][r] + blv[j];
  __syncthreads();
  // LN: 4 threads per token, each 32 channels
  int m = t >> 2, qtr = t & 3;
  float* yr = ys + (size_t)m * 133 + qtr * 32;
  float s = 0.f, q2 = 0.f;
  #pragma unroll
  for (int jj = 0; jj < 8; ++jj) {
    float4 v = *(const float4*)(yr + jj * 4);
    s  += v.x + v.y + v.z + v.w;
    q2 += v.x * v.x + v.y * v.y + v.z * v.z + v.w * v.w;
  }
  s += __shfl_xor(s, 1);  q2 += __shfl_xor(q2, 1);
  s += __shfl_xor(s, 2);  q2 += __shfl_xor(q2, 2);
  float mean = s * (1.f / 128.f);
  float var = fmaxf(q2 * (1.f / 128.f) - mean * mean, 0.f);
  float rstd = rsqrtf(var + 1e-6f);
  #pragma unroll
  for (int jj = 0; jj < 8; ++jj) {
    int c = qtr * 32 + jj * 4;
    float4 v = *(const float4*)(yr + jj * 4);
    float4 g = *(const float4*)(gam + blk * 128 + c);
    float4 e = *(const float4*)(bet + blk * 128 + c);
    float4 r;
    r.x = (v.x - mean) * rstd * g.x + e.x;
    r.y = (v.y - mean) * rstd * g.y + e.y;
    r.z = (v.z - mean) * rstd * g.z + e.z;
    r.w = (v.w - mean) * rstd * g.w + e.w;
    if (DOGELU) { r.x = gelu(r.x); r.y = gelu(r.y); r.z = gelu(r.z); r.w = gelu(r.w); }
    if (OUTMODE == 0) {
      *(float4*)((float*)outv + (tok0 + m) * 128 + c) = r;
    } else if (OUTMODE == 1) {
      bf16 o[4] = {f2b(r.x), f2b(r.y), f2b(r.z), f2b(r.w)};
      *(ushort4*)((bf16*)outv + (tok0 + m) * 128 + c) = *(ushort4*)o;
    } else {
      *(float4*)(yr + jj * 4) = r;   // write back for transposed pass
    }
  }
  if (OUTMODE == 2) {
    __syncthreads();
    // transposed store: out[b*128+c][l0 + l], 2 threads per c (32 l each)
    int b = (int)(tok0 >> 12), l0 = (int)(tok0 & 4095);
    int c = t >> 1, lh = (t & 1) * 32;
    bf16 tmp[32];
    #pragma unroll
    for (int i = 0; i < 32; ++i) tmp[i] = f2b(ys[(size_t)(lh + i) * 133 + c]);
    bf16* dst = (bf16*)outv + ((size_t)b * 128 + c) * 4096 + l0 + lh;
    #pragma unroll
    for (int i = 0; i < 4; ++i) *(uint4*)(dst + i * 8) = *(uint4*)(tmp + i * 8);
  }
}

// ---- depthwise 3x3x3 + bias + LN + GELU. Baseline (verified): 512 thr, f32 halo. ----
__global__ __launch_bounds__(512) void k_dw_ln(
    const float* __restrict__ in, float* __restrict__ out,
    const float* __restrict__ W, const float* __restrict__ bias,
    const float* __restrict__ gam, const float* __restrict__ bet, int blk) {
  __shared__ __align__(16) float ls[9][16][128];   // 73,728 B
  __shared__ __align__(16) float dww[27][128];     // 13,824 B
  int t = threadIdx.x;
  int xg = blockIdx.x & 15, yg = (blockIdx.x >> 4) & 15, b = blockIdx.x >> 8;
  const float* base = in + (((size_t)b) << 12) * 128;
  const float* Wb = W + (size_t)blk * 3456;
  for (int idx = t; idx < 3456; idx += 512) {
    int tap = idx >> 7, c = idx & 127;
    dww[tap][c] = Wb[c * 27 + tap];
  }
  {
    int c4 = (t & 31) * 4, zz = t >> 5;   // zz 0..15
    for (int col = 0; col < 9; ++col) {
      int yy = yg + col / 3 - 1, xx = xg + col % 3 - 1;
      bool ok = ((unsigned)yy < 16u) && ((unsigned)xx < 16u);
      float4 v = {0.f, 0.f, 0.f, 0.f};
      if (ok) v = *(const float4*)(base + ((size_t)((zz << 8) | (yy << 4) | xx)) * 128 + c4);
      *(float4*)&ls[col][zz][c4] = v;
    }
  }
  __syncthreads();
  int q = t & 31, zg = t >> 5;   // zg 0..15 = z
  int c0 = q * 4;
  float4 bias4 = *(const float4*)(bias + blk * 128 + c0);
  float acc[4] = {bias4.x, bias4.y, bias4.z, bias4.w};
  #pragma unroll
  for (int ky = 0; ky < 3; ++ky) {
    #pragma unroll
    for (int kx = 0; kx < 3; ++kx) {
      int col = ky * 3 + kx;
      #pragma unroll
      for (int kz = 0; kz < 3; ++kz) {
        int z = zg + kz - 1;
        float4 v = {0.f, 0.f, 0.f, 0.f};
        if ((unsigned)z < 16u) v = *(const float4*)&ls[col][z][c0];
        float4 w4 = *(const float4*)&dww[kz * 9 + col][c0];
        acc[0] += w4.x * v.x;
        acc[1] += w4.y * v.y;
        acc[2] += w4.z * v.z;
        acc[3] += w4.w * v.w;
      }
    }
  }
  float4 g4 = *(const float4*)(gam + blk * 128 + c0);
  float4 e4 = *(const float4*)(bet + blk * 128 + c0);
  float s  = acc[0] + acc[1] + acc[2] + acc[3];
  float qq = acc[0] * acc[0] + acc[1] * acc[1] + acc[2] * acc[2] + acc[3] * acc[3];
  #pragma unroll
  for (int off = 16; off; off >>= 1) {
    s  += __shfl_down(s, off, 32);
    qq += __shfl_down(qq, off, 32);
  }
  s = __shfl(s, 0, 32); qq = __shfl(qq, 0, 32);
  float mean = s * (1.f / 128.f);
  float var = fmaxf(qq * (1.f / 128.f) - mean * mean, 0.f);
  float rstd = rsqrtf(var + 1e-6f);
  float4 r;
  r.x = gelu((acc[0] - mean) * rstd * g4.x + e4.x);
  r.y = gelu((acc[1] - mean) * rstd * g4.y + e4.y);
  r.z = gelu((acc[2] - mean) * rstd * g4.z + e4.z);
  r.w = gelu((acc[3] - mean) * rstd * g4.w + e4.w);
  *(float4*)(out + (((size_t)b << 12) | (zg << 8) | (yg << 4) | xg) * 128 + c0) = r;
}

// ---- qk via MFMA, split-K partials (deterministic: no atomics). ----
// part layout: [ls 0..7][b][c 0..127][k 0..511] f32; each block writes its own tile.
__global__ __launch_bounds__(256) void k_qk_mfma(
    const bf16* __restrict__ qT, const bf16* __restrict__ kT,
    float* __restrict__ part) {
  __shared__ __align__(16) bf16 qs[128 * 72];
  __shared__ __align__(16) bf16 ks[128 * 72];
  int ls = blockIdx.x, ki = blockIdx.y, b = blockIdx.z;
  const bf16* qb = qT + ((size_t)b * 128) * 4096;
  const bf16* kb = kT + (((size_t)ki * 8 + b) * 128) * 4096;
  int t = threadIdx.x;
  int w = t >> 6, lane = t & 63;
  int wm = (w >> 1) * 64, wo = (w & 1) * 64;
  int cl = lane & 15, q = lane >> 4;
  f32x4 acc[4][4] = {};
  for (int lc = 0; lc < 8; ++lc) {
    int l0 = ls * 512 + lc * 64;
    #pragma unroll
    for (int p = 0; p < 4; ++p) {
      int idx = p * 256 + t;
      int r = idx >> 3, l8 = (idx & 7) * 8;
      *(uint4*)(qs + r * 72 + l8) = *(const uint4*)(qb + (size_t)r * 4096 + l0 + l8);
      *(uint4*)(ks + r * 72 + l8) = *(const uint4*)(kb + (size_t)r * 4096 + l0 + l8);
    }
    __syncthreads();
    #pragma unroll
    for (int kstep = 0; kstep < 2; ++kstep) {
      int kk = kstep * 32 + q * 8;
      short8 a[4], bb[4];
      #pragma unroll
      for (int i = 0; i < 4; ++i) a[i]  = *(const short8*)(qs + (wm + i * 16 + cl) * 72 + kk);
      #pragma unroll
      for (int j = 0; j < 4; ++j) bb[j] = *(const short8*)(ks + (wo + j * 16 + cl) * 72 + kk);
      #pragma unroll
      for (int i = 0; i < 4; ++i)
        #pragma unroll
        for (int j = 0; j < 4; ++j)
          acc[i][j] = __builtin_amdgcn_mfma_f32_16x16x32_bf16(a[i], bb[j], acc[i][j], 0, 0, 0);
    }
    __syncthreads();
  }
  float* pb = part + (((size_t)ls * 8 + b) * 128) * 512;
  #pragma unroll
  for (int i = 0; i < 4; ++i)
    #pragma unroll
    for (int j = 0; j < 4; ++j)
      #pragma unroll
      for (int r = 0; r < 4; ++r) {
        int c = wm + i * 16 + q * 4 + r;
        int k = ki * 128 + wo + j * 16 + cl;
        pb[(size_t)c * 512 + k] = acc[i][j][r];
      }
}

// masked softmax over k=512 per (b,c) row; fixed-order sum of 8 split-K partials; scale = 1/64.
__global__ __launch_bounds__(128) void k_sm(const float* __restrict__ part,
                                            float* __restrict__ attn,
                                            const int* __restrict__ mask) {
  __shared__ float rm[2], rs[2];
  int bc = blockIdx.x;             // b*128 + c
  int b = bc >> 7;
  float* row = attn + (size_t)bc * 512;
  int t = threadIdx.x;
  float v[4];
  #pragma unroll
  for (int j = 0; j < 4; ++j) {
    int k = t + j * 128;
    float s = 0.f;
    #pragma unroll
    for (int ls = 0; ls < 8; ++ls)
      s += part[((((size_t)ls * 8 + b) * 128 + (bc & 127)) * 512) + k];
    v[j] = (mask[b * 4 + j] > 0) ? s * 0.015625f : -1e30f;
  }
  float m = fmaxf(fmaxf(v[0], v[1]), fmaxf(v[2], v[3]));
  #pragma unroll
  for (int off = 32; off; off >>= 1) m = fmaxf(m, __shfl_down(m, off));
  if ((t & 63) == 0) rm[t >> 6] = m;
  __syncthreads();
  m = fmaxf(rm[0], rm[1]);
  float e[4], s = 0.f;
  #pragma unroll
  for (int j = 0; j < 4; ++j) { e[j] = expf(v[j] - m); s += e[j]; }
  #pragma unroll
  for (int off = 32; off; off >>= 1) s += __shfl_down(s, off);
  if ((t & 63) == 0) rs[t >> 6] = s;
  __syncthreads();
  float inv = 1.f / (rs[0] + rs[1]);
  #pragma unroll
  for (int j = 0; j < 4; ++j) row[t + j * 128] = e[j] * inv;
}

// ---- av via MFMA ----
__global__ __launch_bounds__(256) void k_av_mfma(
    const float* __restrict__ attn, const bf16* __restrict__ vball,
    float* __restrict__ xout) {
  __shared__ __align__(16) bf16 vs[128 * 72];
  __shared__ __align__(16) bf16 ps[128 * 72];
  int lt = blockIdx.x, b = blockIdx.y;
  int t = threadIdx.x;
  int w = t >> 6, lane = t & 63;
  int wm = (w >> 1) * 64, wo = (w & 1) * 64;
  int cl = lane & 15, q = lane >> 4;
  f32x4 acc[4][4] = {};
  for (int ki = 0; ki < 4; ++ki) {
    const bf16* vbp = vball + (((size_t)ki * 8 + b) * L) * 128;
    for (int kc = 0; kc < 2; ++kc) {
      #pragma unroll
      for (int p = 0; p < 4; ++p) {
        int idx = p * 256 + t;
        int r = idx >> 3, k8 = (idx & 7) * 8;
        *(uint4*)(vs + r * 72 + k8) =
            *(const uint4*)(vbp + (size_t)(lt * 128 + r) * 128 + kc * 64 + k8);
      }
      #pragma unroll
      for (int p = 0; p < 8; ++p) {
        int idx = p * 256 + t;
        int c = idx >> 4, k4 = (idx & 15) * 4;
        float4 v = *(const float4*)&attn[((size_t)b * 128 + c) * 512 + ki * 128 + kc * 64 + k4];
        bf16 o[4] = {f2b(v.x), f2b(v.y), f2b(v.z), f2b(v.w)};
        *(ushort4*)(ps + c * 72 + k4) = *(ushort4*)o;
      }
      __syncthreads();
      #pragma unroll
      for (int kstep = 0; kstep < 2; ++kstep) {
        int kk = kstep * 32 + q * 8;
        short8 a[4], bb[4];
        #pragma unroll
        for (int i = 0; i < 4; ++i) a[i]  = *(const short8*)(vs + (wm + i * 16 + cl) * 72 + kk);
        #pragma unroll
        for (int j = 0; j < 4; ++j) bb[j] = *(const short8*)(ps + (wo + j * 16 + cl) * 72 + kk);
        #pragma unroll
        for (int i = 0; i < 4; ++i)
          #pragma unroll
          for (int j = 0; j < 4; ++j)
            acc[i][j] = __builtin_amdgcn_mfma_f32_16x16x32_bf16(a[i], bb[j], acc[i][j], 0, 0, 0);
      }
      __syncthreads();
    }
  }
  #pragma unroll
  for (int i = 0; i < 4; ++i)
    #pragma unroll
    for (int j = 0; j < 4; ++j)
      #pragma unroll
      for (int r = 0; r < 4; ++r) {
        int l = lt * 128 + wm + i * 16 + q * 4 + r;
        int c = wo + j * 16 + cl;
        xout[((size_t)b * L + l) * 128 + c] = acc[i][j][r];
      }
}

// out[b,c,l] = query[b,c,l] + x9[b,l,c]
__global__ __launch_bounds__(256) void k_final(
    const void* __restrict__ qv, const float* __restrict__ xin, void* __restrict__ outv,
    const int* __restrict__ flagp) {
  __shared__ float tl[32][33];
  bool isb = (*flagp != 0);
  int l0 = blockIdx.x * 32, c0 = blockIdx.y * 32, b = blockIdx.z;
  int t = threadIdx.x;
  int cc = t & 31, lr = t >> 5;
  #pragma unroll
  for (int p = 0; p < 4; ++p) {
    int l = l0 + lr + p * 8;
    tl[lr + p * 8][cc] = xin[((((size_t)b) << 12) + l) * 128 + c0 + cc];
  }
  __syncthreads();
  int lw = t & 31, cr = t >> 5;
  #pragma unroll
  for (int p = 0; p < 4; ++p) {
    int c = c0 + cr + p * 8;
    size_t idx = (((size_t)b * 128 + c) << 12) + l0 + lw;
    float qf = isb ? b2f(((const bf16*)qv)[idx]) : ((const float*)qv)[idx];
    float r = qf + tl[lw][cr + p * 8];
    if (isb) ((bf16*)outv)[idx] = f2b(r);
    else     ((float*)outv)[idx] = r;
  }
}

extern "C" void kernel_launch(void* const* d_in, const int* in_sizes, int n_in,
                              void* d_out, int out_size, void* d_ws, size_t ws_size,
                              hipStream_t stream) {
  const void* vols[5] = {d_in[0], d_in[1], d_in[2], d_in[3], d_in[4]};
  const int* mask = (const int*)d_in[5];

  char* ws = (char*)d_ws;
  int*   flag  = (int*)(ws + OFF_FLAG);
  float* wts   = (float*)(ws + OFF_WTS);
  bf16*  whi1  = (bf16*)(ws + OFF_WHI1);
  bf16*  wlo1  = (bf16*)(ws + OFF_WLO1);
  bf16*  whi2  = (bf16*)(ws + OFF_WHI2);
  bf16*  wlo2  = (bf16*)(ws + OFF_WLO2);
  float* bufT  = (float*)(ws + OFF_T);
  float* bufA  = (float*)(ws + OFF_A);
  float* bufB  = (float*)(ws + OFF_BB);
  float* xattn = (float*)(ws + OFF_X);    // qk partials first, then attention output
  float* attn  = (float*)(ws + OFF_ATT);
  bf16*  qT    = (bf16*)(ws + OFF_QT);
  bf16*  kT    = (bf16*)(ws + OFF_KT);
  bf16*  vb    = (bf16*)(ws + OFF_VB);

  k_sniff<<<1, 64, 0, stream>>>((const unsigned*)d_in[0], flag);

  const size_t woff[12] = {W_PW1, W_PW1B, W_LN1G, W_LN1B, W_DWW, W_DWB,
                           W_LN2G, W_LN2B, W_PW2, W_PW2B, W_LN3G, W_LN3B};
  for (int i = 0; i < 12; ++i) {
    int n = in_sizes[6 + i];
    if (i == 0)
      k_cvtw<<<(n + 255) / 256, 256, 0, stream>>>(d_in[6 + i], wts + woff[i], whi1, wlo1, n, flag);
    else if (i == 8)
      k_cvtw<<<(n + 255) / 256, 256, 0, stream>>>(d_in[6 + i], wts + woff[i], whi2, wlo2, n, flag);
    else
      k_cvt<<<(n + 255) / 256, 256, 0, stream>>>(d_in[6 + i], wts + woff[i], n, flag);
  }
  const float *pw1_b = wts + W_PW1B, *ln1_g = wts + W_LN1G, *ln1_b = wts + W_LN1B;
  const float *dw_w = wts + W_DWW, *dw_b = wts + W_DWB, *ln2_g = wts + W_LN2G, *ln2_b = wts + W_LN2B;
  const float *pw2_b = wts + W_PW2B, *ln3_g = wts + W_LN3G, *ln3_b = wts + W_LN3B;

  dim3 tg(L / 32, 4, 8);

  // chain: (bufT f32 in) -> pw1 -> bufA -> dw -> bufB -> pw2 -> dst (mode-dependent)
  auto chain = [&]<int OM>(std::integral_constant<int, OM>, const float* src, int blk, void* dst) {
    k_pw_mfma<true, true, 0><<<512, 256, 0, stream>>>(src, bufA, whi1, wlo1, pw1_b, ln1_g, ln1_b, blk, flag);
    k_dw_ln<<<2048, 512, 0, stream>>>(bufA, bufB, dw_w, dw_b, ln2_g, ln2_b, blk);
    k_pw_mfma<false, false, OM><<<512, 256, 0, stream>>>(bufB, dst, whi2, wlo2, pw2_b, ln3_g, ln3_b, blk, flag);
  };

  // q stream
  k_transpose<<<tg, 256, 0, stream>>>(vols[0], bufT, flag);
  chain(std::integral_constant<int, 2>{}, bufT, 0, qT);

  // K + V streams share one transpose per modality
  for (int m = 1; m <= 4; ++m) {
    k_transpose<<<tg, 256, 0, stream>>>(vols[m], bufT, flag);
    chain(std::integral_constant<int, 2>{}, bufT, m,     kT + (size_t)(m - 1) * VOLE);
    chain(std::integral_constant<int, 1>{}, bufT, 4 + m, vb + (size_t)(m - 1) * VOLE);
  }

  // attention: qk writes split-K partials into X region (deterministic, no atomics);
  // sm reduces partials in fixed order; av overwrites X with the attention output.
  k_qk_mfma<<<dim3(8, 4, 8), 256, 0, stream>>>(qT, kT, xattn);
  k_sm<<<(int)(B * 128), 128, 0, stream>>>(xattn, attn, mask);
  k_av_mfma<<<dim3(32, 8), 256, 0, stream>>>(attn, vb, xattn);

  // block 9 then residual
  k_pw_mfma<true, false, 0><<<512, 256, 0, stream>>>(xattn, bufA, whi1, wlo1, pw1_b, ln1_g, ln1_b, 9, flag);
  k_dw_ln<<<2048, 512, 0, stream>>>(bufA, bufB, dw_w, dw_b, ln2_g, ln2_b, 9);
  k_pw_mfma<false, false, 0><<<512, 256, 0, stream>>>(bufB, bufA, whi2, wlo2, pw2_b, ln3_g, ln3_b, 9, flag);
  k_final<<<dim3(L / 32, 4, 8), 256, 0, stream>>>(vols[0], bufA, d_out, flag);
}

// Round 10
// 1069.554 us; speedup vs baseline: 1.0294x; 1.0209x over previous
//
#include <hip/hip_runtime.h>
#include <hip/hip_bf16.h>

typedef __hip_bfloat16 bf16;
#define DEV __device__ __forceinline__

DEV float b2f(bf16 x) { return __bfloat162float(x); }
DEV bf16  f2b(float x) { return __float2bfloat16(x); }

typedef __attribute__((ext_vector_type(8))) short short8;   // 8 bf16 (4 VGPRs)
typedef __attribute__((ext_vector_type(4))) float f32x4;

static constexpr int B = 8, C = 128, S = 16;
static constexpr int L = S * S * S;                 // 4096
static constexpr size_t BL   = (size_t)B * L;       // 32768 tokens
static constexpr size_t VOLE = BL * C;              // 4,194,304 elements / volume

// ---- canonical f32 weight region (element offsets) ----
static constexpr size_t W_PW1  = 0;
static constexpr size_t W_PW1B = 163840;
static constexpr size_t W_LN1G = 165120;
static constexpr size_t W_LN1B = 166400;
static constexpr size_t W_DWW  = 167680;
static constexpr size_t W_DWB  = 202240;
static constexpr size_t W_LN2G = 203520;
static constexpr size_t W_LN2B = 204800;
static constexpr size_t W_PW2  = 206080;
static constexpr size_t W_PW2B = 369920;
static constexpr size_t W_LN3G = 371200;
static constexpr size_t W_LN3B = 372480;

// ---- workspace layout (bytes). 148,897,792 total (same as verified baseline). ----
static constexpr size_t OFF_FLAG = 0;
static constexpr size_t OFF_WTS  = 256;
static constexpr size_t OFF_WHI1 = 1572864;
static constexpr size_t OFF_WLO1 = OFF_WHI1 + 327680;
static constexpr size_t OFF_WHI2 = OFF_WLO1 + 327680;
static constexpr size_t OFF_WLO2 = OFF_WHI2 + 327680;
static constexpr size_t OFF_T    = 4u << 20;                // f32 [B,L,C] transposed vol (persist)
static constexpr size_t OFF_A    = OFF_T  + VOLE * 4;       // f32 chain temp
static constexpr size_t OFF_BB   = OFF_A  + VOLE * 4;       // f32 chain temp
static constexpr size_t OFF_X    = OFF_BB + VOLE * 4;       // f32: qk partials [8][B,128,512] then attn out [B,L,C]
static constexpr size_t OFF_ATT  = OFF_X  + VOLE * 4;       // f32 [B,128,512] softmax probs
static constexpr size_t OFF_QT   = OFF_ATT + (size_t)B * 128 * 512 * 4; // bf16 [B,C,L]
static constexpr size_t OFF_KT   = OFF_QT + VOLE * 2;       // bf16 [4][B,C,L]
static constexpr size_t OFF_VB   = OFF_KT + VOLE * 8;       // bf16 [4][B,L,C]
static constexpr size_t WS_END   = OFF_VB + VOLE * 8;       // 148,897,792

DEV float gelu(float x) { return 0.5f * x * (1.f + erff(x * 0.70710678118654752f)); }

__global__ void k_sniff(const unsigned* __restrict__ q, int* __restrict__ flag) {
  int t = threadIdx.x;
  unsigned u = q[t];
  int good = 0;
  #pragma unroll
  for (int h = 0; h < 2; ++h) {
    unsigned hb = (h ? (u & 0xffff0000u) : (u << 16));
    float v = __uint_as_float(hb);
    float a = fabsf(v);
    if (v == 0.f || (a > 1e-20f && a < 100.f)) good++;
  }
  #pragma unroll
  for (int off = 32; off; off >>= 1) good += __shfl_down(good, off);
  if (t == 0) *flag = (good >= 112) ? 1 : 0;
}

__global__ void k_cvt(const void* __restrict__ src, float* __restrict__ dst, int n,
                      const int* __restrict__ flagp) {
  int i = blockIdx.x * 256 + threadIdx.x;
  if (i >= n) return;
  if (*flagp) dst[i] = b2f(((const bf16*)src)[i]);
  else        dst[i] = ((const float*)src)[i];
}

__global__ void k_cvtw(const void* __restrict__ src, float* __restrict__ dst,
                       bf16* __restrict__ dhi, bf16* __restrict__ dlo, int n,
                       const int* __restrict__ flagp) {
  int i = blockIdx.x * 256 + threadIdx.x;
  if (i >= n) return;
  float v = (*flagp) ? b2f(((const bf16*)src)[i]) : ((const float*)src)[i];
  dst[i] = v;
  bf16 h = f2b(v);
  dhi[i] = h;
  dlo[i] = f2b(v - b2f(h));
}

// [B,C,L] -> [B,L,C] for ONE volume, LDS-tiled, dtype-branched loads, f32 out.
__global__ __launch_bounds__(256) void k_transpose(const void* __restrict__ sv,
                                                   float* __restrict__ d,
                                                   const int* __restrict__ flagp) {
  __shared__ float t[32][33];
  bool isb = (*flagp != 0);
  int b = blockIdx.z;
  int c0 = blockIdx.y * 32, l0 = blockIdx.x * 32;
  int tid = threadIdx.x;
  int lr = tid & 31, cr = tid >> 5;
  #pragma unroll
  for (int i = 0; i < 4; ++i) {
    size_t si = ((size_t)b * C + (c0 + cr + i * 8)) * L + l0 + lr;
    t[cr + i * 8][lr] = isb ? b2f(((const bf16*)sv)[si]) : ((const float*)sv)[si];
  }
  __syncthreads();
  int cw = tid & 31, lw = tid >> 5;
  #pragma unroll
  for (int i = 0; i < 4; ++i) {
    int l = l0 + lw + i * 8;
    d[((size_t)b * L + l) * C + c0 + cw] = t[cw][lw + i * 8];
  }
}

// ---- pointwise conv via split-precision MFMA + fused bias+LN(+GELU) + fused output cast. ----
// Tile 64 tokens x 128 outputs, 256 thr (4 waves), grid 512. LDS 34.8 KB -> 4 blocks/CU cap.
// OUTMODE: 0 = f32 [l][c], 1 = bf16 [l][c], 2 = bf16 [c][l] (transposed, for q/K).
template <bool DOGELU, bool XEXACT, int OUTMODE>
__global__ __launch_bounds__(256) void k_pw_mfma(
    const float* __restrict__ in, void* __restrict__ outv,
    const bf16* __restrict__ Whi, const bf16* __restrict__ Wlo,
    const float* __restrict__ bias,
    const float* __restrict__ gam, const float* __restrict__ bet, int blk,
    const int* __restrict__ flagp) {
  __shared__ __align__(16) char smem[64 * 136 * 2 * 2];   // 34,816 B
  bf16* xh = (bf16*)smem;                                 // [64][136]
  bf16* xl = (bf16*)(smem + 64 * 136 * 2);
  float* ys = (float*)smem;                               // [64][133] = 34,048 B (alias)
  int t = threadIdx.x;
  bool ex = XEXACT && (*flagp != 0);
  size_t tok0 = (size_t)blockIdx.x * 64;
  const bf16* Wh = Whi + ((size_t)blk << 14);
  const bf16* Wl = Wlo + ((size_t)blk << 14);
  // stage x hi/lo: 64 tokens x 128 ch
  #pragma unroll
  for (int p = 0; p < 8; ++p) {
    int idx = p * 256 + t;
    int m = idx >> 5, c4 = (idx & 31) * 4;
    float4 v = *(const float4*)(in + (tok0 + m) * 128 + c4);
    bf16 hi[4] = {f2b(v.x), f2b(v.y), f2b(v.z), f2b(v.w)};
    *(ushort4*)(xh + m * 136 + c4) = *(ushort4*)hi;
    if (!ex) {
      bf16 lo[4] = {f2b(v.x - b2f(hi[0])), f2b(v.y - b2f(hi[1])),
                    f2b(v.z - b2f(hi[2])), f2b(v.w - b2f(hi[3]))};
      *(ushort4*)(xl + m * 136 + c4) = *(ushort4*)lo;
    }
  }
  __syncthreads();
  int w = t >> 6, lane = t & 63;
  int wm = (w & 1) * 32, wo = (w >> 1) * 64;   // wave: 32 tokens x 64 outputs
  int cl = lane & 15, q = lane >> 4;
  f32x4 acc[2][4] = {};
  #pragma unroll
  for (int ks = 0; ks < 4; ++ks) {
    int k = ks * 32 + q * 8;
    short8 ah[2], al[2], bh[4], blo[4];
    #pragma unroll
    for (int i = 0; i < 2; ++i) {
      ah[i] = *(const short8*)(xh + (wm + i * 16 + cl) * 136 + k);
      if (!ex) al[i] = *(const short8*)(xl + (wm + i * 16 + cl) * 136 + k);
    }
    #pragma unroll
    for (int j = 0; j < 4; ++j) {
      size_t wi = (size_t)(wo + j * 16 + cl) * 128 + k;
      bh[j]  = *(const short8*)(Wh + wi);
      blo[j] = *(const short8*)(Wl + wi);
    }
    #pragma unroll
    for (int i = 0; i < 2; ++i)
      #pragma unroll
      for (int j = 0; j < 4; ++j) {
        acc[i][j] = __builtin_amdgcn_mfma_f32_16x16x32_bf16(ah[i], bh[j],  acc[i][j], 0, 0, 0);
        acc[i][j] = __builtin_amdgcn_mfma_f32_16x16x32_bf16(ah[i], blo[j], acc[i][j], 0, 0, 0);
        if (!ex)
          acc[i][j] = __builtin_amdgcn_mfma_f32_16x16x32_bf16(al[i], bh[j], acc[i][j], 0, 0, 0);
      }
  }
  float blv[4];
  #pragma unroll
  for (int j = 0; j < 4; ++j) blv[j] = bias[blk * 128 + wo + j * 16 + cl];
  __syncthreads();
  // park D+bias into ys[64][133]
  #pragma unroll
  for (int i = 0; i < 2; ++i)
    #pragma unroll
    for (int j = 0; j < 4; ++j)
      #pragma unroll
      for (int r = 0; r < 4; ++r)
        ys[(wm + i * 16 + q * 4 + r) * 133 + wo + j * 16 + cl] = acc[i][j][r] + blv[j];
  __syncthreads();
  // LN: 4 threads per token, each 32 channels
  int m = t >> 2, qtr = t & 3;
  float* yr = ys + (size_t)m * 133 + qtr * 32;
  float s = 0.f, q2 = 0.f;
  #pragma unroll
  for (int jj = 0; jj < 8; ++jj) {
    float4 v = *(const float4*)(yr + jj * 4);
    s  += v.x + v.y + v.z + v.w;
    q2 += v.x * v.x + v.y * v.y + v.z * v.z + v.w * v.w;
  }
  s += __shfl_xor(s, 1);  q2 += __shfl_xor(q2, 1);
  s += __shfl_xor(s, 2);  q2 += __shfl_xor(q2, 2);
  float mean = s * (1.f / 128.f);
  float var = fmaxf(q2 * (1.f / 128.f) - mean * mean, 0.f);
  float rstd = rsqrtf(var + 1e-6f);
  #pragma unroll
  for (int jj = 0; jj < 8; ++jj) {
    int c = qtr * 32 + jj * 4;
    float4 v = *(const float4*)(yr + jj * 4);
    float4 g = *(const float4*)(gam + blk * 128 + c);
    float4 e = *(const float4*)(bet + blk * 128 + c);
    float4 r;
    r.x = (v.x - mean) * rstd * g.x + e.x;
    r.y = (v.y - mean) * rstd * g.y + e.y;
    r.z = (v.z - mean) * rstd * g.z + e.z;
    r.w = (v.w - mean) * rstd * g.w + e.w;
    if (DOGELU) { r.x = gelu(r.x); r.y = gelu(r.y); r.z = gelu(r.z); r.w = gelu(r.w); }
    if (OUTMODE == 0) {
      *(float4*)((float*)outv + (tok0 + m) * 128 + c) = r;
    } else if (OUTMODE == 1) {
      bf16 o[4] = {f2b(r.x), f2b(r.y), f2b(r.z), f2b(r.w)};
      *(ushort4*)((bf16*)outv + (tok0 + m) * 128 + c) = *(ushort4*)o;
    } else {
      *(float4*)(yr + jj * 4) = r;   // write back for transposed pass
    }
  }
  if (OUTMODE == 2) {
    __syncthreads();
    // transposed store: out[b*128+c][l0 + l], 2 threads per c (32 l each)
    int b = (int)(tok0 >> 12), l0 = (int)(tok0 & 4095);
    int c = t >> 1, lh = (t & 1) * 32;
    bf16 tmp[32];
    #pragma unroll
    for (int i = 0; i < 32; ++i) tmp[i] = f2b(ys[(size_t)(lh + i) * 133 + c]);
    bf16* dst = (bf16*)outv + ((size_t)b * 128 + c) * 4096 + l0 + lh;
    #pragma unroll
    for (int i = 0; i < 4; ++i) *(uint4*)(dst + i * 8) = *(uint4*)(tmp + i * 8);
  }
}

// ---- depthwise 3x3x3 + bias + LN + GELU. v3: no halo LDS — direct global (L2) tap reads. ----
// Only dww (13.8 KB) stays in LDS. 27 independent coalesced float4 loads/thread = deep MLP;
// L2 serves the 9x halo overlap.
__global__ __launch_bounds__(512) void k_dw_ln(
    const float* __restrict__ in, float* __restrict__ out,
    const float* __restrict__ W, const float* __restrict__ bias,
    const float* __restrict__ gam, const float* __restrict__ bet, int blk) {
  __shared__ __align__(16) float dww[27][128];     // 13,824 B
  int t = threadIdx.x;
  int xg = blockIdx.x & 15, yg = (blockIdx.x >> 4) & 15, b = blockIdx.x >> 8;
  const float* base = in + (((size_t)b) << 12) * 128;
  const float* Wb = W + (size_t)blk * 3456;
  for (int idx = t; idx < 3456; idx += 512) {
    int tap = idx >> 7, c = idx & 127;
    dww[tap][c] = Wb[c * 27 + tap];
  }
  __syncthreads();
  int q = t & 31, zg = t >> 5;   // zg 0..15 = z
  int c0 = q * 4;
  float4 bias4 = *(const float4*)(bias + blk * 128 + c0);
  float acc[4] = {bias4.x, bias4.y, bias4.z, bias4.w};
  #pragma unroll
  for (int ky = 0; ky < 3; ++ky) {
    #pragma unroll
    for (int kx = 0; kx < 3; ++kx) {
      int col = ky * 3 + kx;
      int yy = yg + ky - 1, xx = xg + kx - 1;
      bool okxy = ((unsigned)yy < 16u) && ((unsigned)xx < 16u);
      #pragma unroll
      for (int kz = 0; kz < 3; ++kz) {
        int z = zg + kz - 1;
        float4 v = {0.f, 0.f, 0.f, 0.f};
        if (okxy && ((unsigned)z < 16u))
          v = *(const float4*)(base + ((size_t)((z << 8) | (yy << 4) | xx)) * 128 + c0);
        float4 w4 = *(const float4*)&dww[kz * 9 + col][c0];
        acc[0] += w4.x * v.x;
        acc[1] += w4.y * v.y;
        acc[2] += w4.z * v.z;
        acc[3] += w4.w * v.w;
      }
    }
  }
  float4 g4 = *(const float4*)(gam + blk * 128 + c0);
  float4 e4 = *(const float4*)(bet + blk * 128 + c0);
  float s  = acc[0] + acc[1] + acc[2] + acc[3];
  float qq = acc[0] * acc[0] + acc[1] * acc[1] + acc[2] * acc[2] + acc[3] * acc[3];
  #pragma unroll
  for (int off = 16; off; off >>= 1) {
    s  += __shfl_down(s, off, 32);
    qq += __shfl_down(qq, off, 32);
  }
  s = __shfl(s, 0, 32); qq = __shfl(qq, 0, 32);
  float mean = s * (1.f / 128.f);
  float var = fmaxf(qq * (1.f / 128.f) - mean * mean, 0.f);
  float rstd = rsqrtf(var + 1e-6f);
  float4 r;
  r.x = gelu((acc[0] - mean) * rstd * g4.x + e4.x);
  r.y = gelu((acc[1] - mean) * rstd * g4.y + e4.y);
  r.z = gelu((acc[2] - mean) * rstd * g4.z + e4.z);
  r.w = gelu((acc[3] - mean) * rstd * g4.w + e4.w);
  *(float4*)(out + (((size_t)b << 12) | (zg << 8) | (yg << 4) | xg) * 128 + c0) = r;
}

// ---- qk via MFMA, split-K partials (deterministic: no atomics). ----
// part layout: [ls 0..7][b][c 0..127][k 0..511] f32; each block writes its own tile.
__global__ __launch_bounds__(256) void k_qk_mfma(
    const bf16* __restrict__ qT, const bf16* __restrict__ kT,
    float* __restrict__ part) {
  __shared__ __align__(16) bf16 qs[128 * 72];
  __shared__ __align__(16) bf16 ks[128 * 72];
  int ls = blockIdx.x, ki = blockIdx.y, b = blockIdx.z;
  const bf16* qb = qT + ((size_t)b * 128) * 4096;
  const bf16* kb = kT + (((size_t)ki * 8 + b) * 128) * 4096;
  int t = threadIdx.x;
  int w = t >> 6, lane = t & 63;
  int wm = (w >> 1) * 64, wo = (w & 1) * 64;
  int cl = lane & 15, q = lane >> 4;
  f32x4 acc[4][4] = {};
  for (int lc = 0; lc < 8; ++lc) {
    int l0 = ls * 512 + lc * 64;
    #pragma unroll
    for (int p = 0; p < 4; ++p) {
      int idx = p * 256 + t;
      int r = idx >> 3, l8 = (idx & 7) * 8;
      *(uint4*)(qs + r * 72 + l8) = *(const uint4*)(qb + (size_t)r * 4096 + l0 + l8);
      *(uint4*)(ks + r * 72 + l8) = *(const uint4*)(kb + (size_t)r * 4096 + l0 + l8);
    }
    __syncthreads();
    #pragma unroll
    for (int kstep = 0; kstep < 2; ++kstep) {
      int kk = kstep * 32 + q * 8;
      short8 a[4], bb[4];
      #pragma unroll
      for (int i = 0; i < 4; ++i) a[i]  = *(const short8*)(qs + (wm + i * 16 + cl) * 72 + kk);
      #pragma unroll
      for (int j = 0; j < 4; ++j) bb[j] = *(const short8*)(ks + (wo + j * 16 + cl) * 72 + kk);
      #pragma unroll
      for (int i = 0; i < 4; ++i)
        #pragma unroll
        for (int j = 0; j < 4; ++j)
          acc[i][j] = __builtin_amdgcn_mfma_f32_16x16x32_bf16(a[i], bb[j], acc[i][j], 0, 0, 0);
    }
    __syncthreads();
  }
  float* pb = part + (((size_t)ls * 8 + b) * 128) * 512;
  #pragma unroll
  for (int i = 0; i < 4; ++i)
    #pragma unroll
    for (int j = 0; j < 4; ++j)
      #pragma unroll
      for (int r = 0; r < 4; ++r) {
        int c = wm + i * 16 + q * 4 + r;
        int k = ki * 128 + wo + j * 16 + cl;
        pb[(size_t)c * 512 + k] = acc[i][j][r];
      }
}

// masked softmax over k=512 per (b,c) row; fixed-order sum of 8 split-K partials; scale = 1/64.
__global__ __launch_bounds__(128) void k_sm(const float* __restrict__ part,
                                            float* __restrict__ attn,
                                            const int* __restrict__ mask) {
  __shared__ float rm[2], rs[2];
  int bc = blockIdx.x;             // b*128 + c
  int b = bc >> 7;
  float* row = attn + (size_t)bc * 512;
  int t = threadIdx.x;
  float v[4];
  #pragma unroll
  for (int j = 0; j < 4; ++j) {
    int k = t + j * 128;
    float s = 0.f;
    #pragma unroll
    for (int ls = 0; ls < 8; ++ls)
      s += part[((((size_t)ls * 8 + b) * 128 + (bc & 127)) * 512) + k];
    v[j] = (mask[b * 4 + j] > 0) ? s * 0.015625f : -1e30f;
  }
  float m = fmaxf(fmaxf(v[0], v[1]), fmaxf(v[2], v[3]));
  #pragma unroll
  for (int off = 32; off; off >>= 1) m = fmaxf(m, __shfl_down(m, off));
  if ((t & 63) == 0) rm[t >> 6] = m;
  __syncthreads();
  m = fmaxf(rm[0], rm[1]);
  float e[4], s = 0.f;
  #pragma unroll
  for (int j = 0; j < 4; ++j) { e[j] = expf(v[j] - m); s += e[j]; }
  #pragma unroll
  for (int off = 32; off; off >>= 1) s += __shfl_down(s, off);
  if ((t & 63) == 0) rs[t >> 6] = s;
  __syncthreads();
  float inv = 1.f / (rs[0] + rs[1]);
  #pragma unroll
  for (int j = 0; j < 4; ++j) row[t + j * 128] = e[j] * inv;
}

// ---- av via MFMA ----
__global__ __launch_bounds__(256) void k_av_mfma(
    const float* __restrict__ attn, const bf16* __restrict__ vball,
    float* __restrict__ xout) {
  __shared__ __align__(16) bf16 vs[128 * 72];
  __shared__ __align__(16) bf16 ps[128 * 72];
  int lt = blockIdx.x, b = blockIdx.y;
  int t = threadIdx.x;
  int w = t >> 6, lane = t & 63;
  int wm = (w >> 1) * 64, wo = (w & 1) * 64;
  int cl = lane & 15, q = lane >> 4;
  f32x4 acc[4][4] = {};
  for (int ki = 0; ki < 4; ++ki) {
    const bf16* vbp = vball + (((size_t)ki * 8 + b) * L) * 128;
    for (int kc = 0; kc < 2; ++kc) {
      #pragma unroll
      for (int p = 0; p < 4; ++p) {
        int idx = p * 256 + t;
        int r = idx >> 3, k8 = (idx & 7) * 8;
        *(uint4*)(vs + r * 72 + k8) =
            *(const uint4*)(vbp + (size_t)(lt * 128 + r) * 128 + kc * 64 + k8);
      }
      #pragma unroll
      for (int p = 0; p < 8; ++p) {
        int idx = p * 256 + t;
        int c = idx >> 4, k4 = (idx & 15) * 4;
        float4 v = *(const float4*)&attn[((size_t)b * 128 + c) * 512 + ki * 128 + kc * 64 + k4];
        bf16 o[4] = {f2b(v.x), f2b(v.y), f2b(v.z), f2b(v.w)};
        *(ushort4*)(ps + c * 72 + k4) = *(ushort4*)o;
      }
      __syncthreads();
      #pragma unroll
      for (int kstep = 0; kstep < 2; ++kstep) {
        int kk = kstep * 32 + q * 8;
        short8 a[4], bb[4];
        #pragma unroll
        for (int i = 0; i < 4; ++i) a[i]  = *(const short8*)(vs + (wm + i * 16 + cl) * 72 + kk);
        #pragma unroll
        for (int j = 0; j < 4; ++j) bb[j] = *(const short8*)(ps + (wo + j * 16 + cl) * 72 + kk);
        #pragma unroll
        for (int i = 0; i < 4; ++i)
          #pragma unroll
          for (int j = 0; j < 4; ++j)
            acc[i][j] = __builtin_amdgcn_mfma_f32_16x16x32_bf16(a[i], bb[j], acc[i][j], 0, 0, 0);
      }
      __syncthreads();
    }
  }
  #pragma unroll
  for (int i = 0; i < 4; ++i)
    #pragma unroll
    for (int j = 0; j < 4; ++j)
      #pragma unroll
      for (int r = 0; r < 4; ++r) {
        int l = lt * 128 + wm + i * 16 + q * 4 + r;
        int c = wo + j * 16 + cl;
        xout[((size_t)b * L + l) * 128 + c] = acc[i][j][r];
      }
}

// out[b,c,l] = query[b,c,l] + x9[b,l,c]
__global__ __launch_bounds__(256) void k_final(
    const void* __restrict__ qv, const float* __restrict__ xin, void* __restrict__ outv,
    const int* __restrict__ flagp) {
  __shared__ float tl[32][33];
  bool isb = (*flagp != 0);
  int l0 = blockIdx.x * 32, c0 = blockIdx.y * 32, b = blockIdx.z;
  int t = threadIdx.x;
  int cc = t & 31, lr = t >> 5;
  #pragma unroll
  for (int p = 0; p < 4; ++p) {
    int l = l0 + lr + p * 8;
    tl[lr + p * 8][cc] = xin[((((size_t)b) << 12) + l) * 128 + c0 + cc];
  }
  __syncthreads();
  int lw = t & 31, cr = t >> 5;
  #pragma unroll
  for (int p = 0; p < 4; ++p) {
    int c = c0 + cr + p * 8;
    size_t idx = (((size_t)b * 128 + c) << 12) + l0 + lw;
    float qf = isb ? b2f(((const bf16*)qv)[idx]) : ((const float*)qv)[idx];
    float r = qf + tl[lw][cr + p * 8];
    if (isb) ((bf16*)outv)[idx] = f2b(r);
    else     ((float*)outv)[idx] = r;
  }
}

extern "C" void kernel_launch(void* const* d_in, const int* in_sizes, int n_in,
                              void* d_out, int out_size, void* d_ws, size_t ws_size,
                              hipStream_t stream) {
  const void* vols[5] = {d_in[0], d_in[1], d_in[2], d_in[3], d_in[4]};
  const int* mask = (const int*)d_in[5];

  char* ws = (char*)d_ws;
  int*   flag  = (int*)(ws + OFF_FLAG);
  float* wts   = (float*)(ws + OFF_WTS);
  bf16*  whi1  = (bf16*)(ws + OFF_WHI1);
  bf16*  wlo1  = (bf16*)(ws + OFF_WLO1);
  bf16*  whi2  = (bf16*)(ws + OFF_WHI2);
  bf16*  wlo2  = (bf16*)(ws + OFF_WLO2);
  float* bufT  = (float*)(ws + OFF_T);
  float* bufA  = (float*)(ws + OFF_A);
  float* bufB  = (float*)(ws + OFF_BB);
  float* xattn = (float*)(ws + OFF_X);    // qk partials first, then attention output
  float* attn  = (float*)(ws + OFF_ATT);
  bf16*  qT    = (bf16*)(ws + OFF_QT);
  bf16*  kT    = (bf16*)(ws + OFF_KT);
  bf16*  vb    = (bf16*)(ws + OFF_VB);

  // Zero the entire workspace every launch: guarantees launch N's state == launch 1's
  // state (replay determinism), regardless of any residual read-before-write.
  size_t zlen = ws_size < WS_END ? ws_size : WS_END;
  hipMemsetAsync(d_ws, 0, zlen, stream);

  k_sniff<<<1, 64, 0, stream>>>((const unsigned*)d_in[0], flag);

  const size_t woff[12] = {W_PW1, W_PW1B, W_LN1G, W_LN1B, W_DWW, W_DWB,
                           W_LN2G, W_LN2B, W_PW2, W_PW2B, W_LN3G, W_LN3B};
  for (int i = 0; i < 12; ++i) {
    int n = in_sizes[6 + i];
    if (i == 0)
      k_cvtw<<<(n + 255) / 256, 256, 0, stream>>>(d_in[6 + i], wts + woff[i], whi1, wlo1, n, flag);
    else if (i == 8)
      k_cvtw<<<(n + 255) / 256, 256, 0, stream>>>(d_in[6 + i], wts + woff[i], whi2, wlo2, n, flag);
    else
      k_cvt<<<(n + 255) / 256, 256, 0, stream>>>(d_in[6 + i], wts + woff[i], n, flag);
  }
  const float *pw1_b = wts + W_PW1B, *ln1_g = wts + W_LN1G, *ln1_b = wts + W_LN1B;
  const float *dw_w = wts + W_DWW, *dw_b = wts + W_DWB, *ln2_g = wts + W_LN2G, *ln2_b = wts + W_LN2B;
  const float *pw2_b = wts + W_PW2B, *ln3_g = wts + W_LN3G, *ln3_b = wts + W_LN3B;

  dim3 tg(L / 32, 4, 8);

  // chain: (bufT f32 in) -> pw1 -> bufA -> dw -> bufB -> pw2 -> dst (mode-dependent)
  auto chain = [&]<int OM>(std::integral_constant<int, OM>, const float* src, int blk, void* dst) {
    k_pw_mfma<true, true, 0><<<512, 256, 0, stream>>>(src, bufA, whi1, wlo1, pw1_b, ln1_g, ln1_b, blk, flag);
    k_dw_ln<<<2048, 512, 0, stream>>>(bufA, bufB, dw_w, dw_b, ln2_g, ln2_b, blk);
    k_pw_mfma<false, false, OM><<<512, 256, 0, stream>>>(bufB, dst, whi2, wlo2, pw2_b, ln3_g, ln3_b, blk, flag);
  };

  // q stream
  k_transpose<<<tg, 256, 0, stream>>>(vols[0], bufT, flag);
  chain(std::integral_constant<int, 2>{}, bufT, 0, qT);

  // K + V streams share one transpose per modality
  for (int m = 1; m <= 4; ++m) {
    k_transpose<<<tg, 256, 0, stream>>>(vols[m], bufT, flag);
    chain(std::integral_constant<int, 2>{}, bufT, m,     kT + (size_t)(m - 1) * VOLE);
    chain(std::integral_constant<int, 1>{}, bufT, 4 + m, vb + (size_t)(m - 1) * VOLE);
  }

  // attention: qk writes split-K partials into X region (deterministic, no atomics);
  // sm reduces partials in fixed order; av overwrites X with the attention output.
  k_qk_mfma<<<dim3(8, 4, 8), 256, 0, stream>>>(qT, kT, xattn);
  k_sm<<<(int)(B * 128), 128, 0, stream>>>(xattn, attn, mask);
  k_av_mfma<<<dim3(32, 8), 256, 0, stream>>>(attn, vb, xattn);

  // block 9 then residual
  k_pw_mfma<true, false, 0><<<512, 256, 0, stream>>>(xattn, bufA, whi1, wlo1, pw1_b, ln1_g, ln1_b, 9, flag);
  k_dw_ln<<<2048, 512, 0, stream>>>(bufA, bufB, dw_w, dw_b, ln2_g, ln2_b, 9);
  k_pw_mfma<false, false, 0><<<512, 256, 0, stream>>>(bufB, bufA, whi2, wlo2, pw2_b, ln3_g, ln3_b, 9, flag);
  k_final<<<dim3(L / 32, 4, 8), 256, 0, stream>>>(vols[0], bufA, d_out, flag);
}